// Round 6
// baseline (2760.202 us; speedup 1.0000x reference)
//
#include <hip/hip_runtime.h>

// Problem constants (SIZE=68, SSN=8 -> C=9, S1=69, BATCH=256)
#define C9     9
#define S1     69
#define JT     621            // C9*S1: one (class,pos) plane
#define NBATCH 256
#define NSTEP  68
#define QJ     4761           // 69*69   (Q j-stride, P s-major plane size)
#define QI     42849          // 9*69*69 (Q i-stride; also P batch stride)
#define BROW   42849          // 69 planes * 621 per-batch alpha
#define ALPHA_N (NBATCH*BROW)
#define QTFL   385664         // padded float count of one ws region
#define NEGINF (-__builtin_inff())

// float4 with 4-byte alignment guarantee: rows have odd stride 69 floats, so
// 16B alignment is impossible; gfx950 supports dword-aligned dwordx4.
typedef float float4u __attribute__((ext_vector_type(4), aligned(4)));

// ---------------------------------------------------------------------------
// qw: QW[j][s][i][t] = Q[j][i][s][t].  9 i-values at stride 276 B from one
// base (13-bit immediate-offset friendly) and s-advance = one pointer bump.
__global__ void qw_kernel(const float* __restrict__ Q, float* __restrict__ QW)
{
  const int bl = blockIdx.x;           // j*69 + s
  const int j = bl / S1, s = bl - j*S1;
  float* dst = QW + (size_t)bl*JT;
  const float* src = Q + (size_t)j*QJ + s*S1;
  for (int f = threadIdx.x; f < JT; f += 256){
    const int i = f / S1, t = f - i*S1;
    dst[f] = src[i*QJ + t];
  }
}

// ---------------------------------------------------------------------------
// qtrans: QT[c][t][i][s] = Q[c][i][s][t]  (coalesced backtrace Q reads)
__global__ void qtrans_kernel(const float* __restrict__ Q, float* __restrict__ QT)
{
  __shared__ float tile[69*70];
  const int pl = blockIdx.x;           // c*9 + i
  const int c = pl / 9, i = pl - c*9;
  const float* src = Q + (size_t)pl*QJ;
  for (int f = threadIdx.x; f < QJ; f += 256){
    const int s = f / S1, t = f - s*S1;
    tile[s*70 + t] = src[f];
  }
  __syncthreads();
  float* dst = QT + (size_t)c*QI + i*S1;     // + t*621 + s
  for (int f = threadIdx.x; f < QJ; f += 256){
    const int t = f / S1, s = f - t*S1;
    dst[t*JT + s] = tile[s*70 + t];
  }
}

// ---------------------------------------------------------------------------
// scan12x2: partial max-plus over 12 s rows for TWO batches sharing the same
// Q loads (Q element fetched once from L2, used twice -> halves the per-XCD
// L2-BW floor, the measured bottleneck).  Rolled loop + 2-deep ping-pong:
// proven spill-safe shape (round 3's full unroll spilled; never again).
// SI = Q i-stride (floats), SS = Q s-stride (floats).
template<int SI, int SS>
__device__ __forceinline__ void scan12x2(const float* __restrict__ qb,
                                         const float* __restrict__ pb0,
                                         const float* __restrict__ pb1,
                                         const float* __restrict__ la0,
                                         const float* __restrict__ la1,
                                         const float Tv,
                                         float4u& A0, float4u& A1)
{
#define LD(QB, P0, P1, S) { \
  const float* q_ = qb + (S)*SS; \
  _Pragma("unroll") \
  for (int i_ = 0; i_ < C9; ++i_) QB[i_] = *(const float4u*)(q_ + i_*SI); \
  P0 = *(const float4u*)(pb0 + (S)*S1); \
  P1 = *(const float4u*)(pb1 + (S)*S1); }
#define CM(QB, P0, P1, S) { \
  float r00=NEGINF,r01=NEGINF,r02=NEGINF,r03=NEGINF; \
  float r10=NEGINF,r11=NEGINF,r12=NEGINF,r13=NEGINF; \
  _Pragma("unroll") \
  for (int i_ = 0; i_ < C9; ++i_){ \
    const float l0_ = la0[i_*72 + (S)]; \
    const float l1_ = la1[i_*72 + (S)]; \
    r00 = fmaxf(r00, fmaf(Tv, QB[i_].x, l0_)); \
    r01 = fmaxf(r01, fmaf(Tv, QB[i_].y, l0_)); \
    r02 = fmaxf(r02, fmaf(Tv, QB[i_].z, l0_)); \
    r03 = fmaxf(r03, fmaf(Tv, QB[i_].w, l0_)); \
    r10 = fmaxf(r10, fmaf(Tv, QB[i_].x, l1_)); \
    r11 = fmaxf(r11, fmaf(Tv, QB[i_].y, l1_)); \
    r12 = fmaxf(r12, fmaf(Tv, QB[i_].z, l1_)); \
    r13 = fmaxf(r13, fmaf(Tv, QB[i_].w, l1_)); \
  } \
  A0.x = fmaxf(A0.x, P0.x + r00); A0.y = fmaxf(A0.y, P0.y + r01); \
  A0.z = fmaxf(A0.z, P0.z + r02); A0.w = fmaxf(A0.w, P0.w + r03); \
  A1.x = fmaxf(A1.x, P1.x + r10); A1.y = fmaxf(A1.y, P1.y + r11); \
  A1.z = fmaxf(A1.z, P1.z + r12); A1.w = fmaxf(A1.w, P1.w + r13); }

  float4u qA[C9], qB[C9], pA0, pA1, pB0, pB1;
  int s = 0;
  LD(qA, pA0, pA1, s)
  for (; s + 2 < 12; s += 2){
    LD(qB, pB0, pB1, s+1)
    CM(qA, pA0, pA1, s)
    LD(qA, pA0, pA1, s+2)
    CM(qB, pB0, pB1, s+1)
  }
  // width 12 is even: epilogue handles the final pair
  LD(qB, pB0, pB1, s+1)
  CM(qA, pA0, pA1, s)
  CM(qB, pB0, pB1, s+1)
#undef LD
#undef CM
}

// ---------------------------------------------------------------------------
// mega v6: TWO batches per block, grid 128.  1024 threads = 16 waves:
// 6 s-groups x 162 (j,t-quad) slots, fixed 12-wide s-ranges at
// {0,11,23,34,46,57} (overlaps duplicated -- max idempotent, exact).
// amdgpu_waves_per_eu(4,4): forces the VGPR budget to 128 (the allocator's
// default targets 2 blocks/CU = 8 waves/EU = 64-VGPR cap, which spilled
// scan12's live set in rounds 4/5: WRITE_SIZE 95->307 MB).  One resident
// 1024-thread block/CU is exactly 4 waves/EU.
__global__ __attribute__((amdgpu_waves_per_eu(4, 4)))
__launch_bounds__(1024) void mega_kernel(
    const float* __restrict__ P, const float* __restrict__ Q,
    const float* __restrict__ pi, const float* __restrict__ Tp,
    const int* __restrict__ ls, float* __restrict__ out,
    const float* __restrict__ QW, const float* __restrict__ QT, int wsmode)
{
  __shared__ __align__(16) float la[2][2][C9*72];  // [batch][buf][i*72+s]
  __shared__ __align__(16) float part[5][162][2][4];
  __shared__ float red[2][16];
  __shared__ float m_sh[2][NSTEP+1], lse_sh[2][NSTEP+1], n_sh[2][NSTEP+1];
  __shared__ float sums_sh[2][NSTEP+1][3];
  __shared__ float sbest[2][16];
  __shared__ int   sidx[2][16];
  __shared__ int   sct[4];

  const int tid  = threadIdx.x;
  const int w    = tid >> 6;
  const int lane = tid & 63;
  const int b0   = blockIdx.x * 2;
  const int b1   = b0 + 1;
  const bool act = tid < 972;
  const int gg   = act ? tid / 162 : 5;          // s-group 0..5
  const int slot = act ? tid - gg*162 : 0;
  const int j    = slot / 18;                    // output class 0..8
  const int tq   = slot - j*18;                  // t-quad 0..17
  const int t0   = (tq < 17) ? 4*tq : 65;        // tq=17 owns only t=68
  const int s_lo = (gg*23) >> 1;                 // {0,11,23,34,46,57}
  const float Tv = Tp[0];

  float* out0 = out + (size_t)b0*BROW;
  float* out1 = out + (size_t)b1*BROW;

  // ---- prep: v[0] raw (pi at s==0, else -inf); m[0], lse_v[0] ----
  for (int e = tid; e < JT; e += 1024){
    const int i = e / S1, s = e - i*S1;
    const float v0 = (s == 0) ? pi[i] : NEGINF;
    out0[68*JT + e] = v0;
    out1[68*JT + e] = v0;
    la[0][0][i*72 + s] = v0;
    la[1][0][i*72 + s] = v0;
  }
  if (tid == 0){
    float mx = pi[0];
    #pragma unroll
    for (int c = 1; c < C9; ++c) mx = fmaxf(mx, pi[c]);
    float sm = 0.f;
    #pragma unroll
    for (int c = 0; c < C9; ++c) sm += expf(pi[c] - mx);
    m_sh[0][0] = mx;            m_sh[1][0] = mx;
    lse_sh[0][0] = mx + logf(sm); lse_sh[1][0] = mx + logf(sm);
  }
  __syncthreads();
  float mprev0 = m_sh[0][0];
  float mprev1 = m_sh[1][0];

  const bool useQW = (wsmode >= 1);
  // QW[j][s][i][t]: j-stride QI; s-stride JT; i-stride S1.
  const float* qw_b = QW + (size_t)j*QI + (size_t)s_lo*JT + t0;
  // Raw Q[j][i][s][t]: i-stride QI; s-stride S1.
  const float* qr_b = Q + (size_t)j*QJ + s_lo*S1 + t0;
  const float* p0_b = P + (size_t)(b0*C9 + j)*QJ + s_lo*S1 + t0;
  const float* p1_b = p0_b + QI;                 // batch stride == QI

  // ---- 68 max-plus steps ----
  int cur = 0;
  for (int k = 1; k <= NSTEP; ++k){
    const float* laS0 = la[0][cur] + s_lo;
    const float* laS1 = la[1][cur] + s_lo;
    float4u A0, A1;
    A0.x=A0.y=A0.z=A0.w=NEGINF; A1.x=A1.y=A1.z=A1.w=NEGINF;
    if (act){
      if (useQW) scan12x2<S1, JT>(qw_b, p0_b, p1_b, laS0, laS1, Tv, A0, A1);
      else       scan12x2<QI, S1>(qr_b, p0_b, p1_b, laS0, laS1, Tv, A0, A1);
      if (gg > 0){
        *(float4u*)(&part[gg-1][slot][0][0]) = A0;
        *(float4u*)(&part[gg-1][slot][1][0]) = A1;
      }
    }
    __syncthreads();                                     // (A) partials ready

    float mval0 = NEGINF, mval1 = NEGINF;
    float v00=0.f, v01=0.f, v02=0.f, v03=0.f;
    float v10=0.f, v11=0.f, v12=0.f, v13=0.f;
    if (act && gg == 0){
      float c00=A0.x, c01=A0.y, c02=A0.z, c03=A0.w;
      float c10=A1.x, c11=A1.y, c12=A1.z, c13=A1.w;
      #pragma unroll
      for (int g = 0; g < 5; ++g){
        c00 = fmaxf(c00, part[g][slot][0][0]);
        c01 = fmaxf(c01, part[g][slot][0][1]);
        c02 = fmaxf(c02, part[g][slot][0][2]);
        c03 = fmaxf(c03, part[g][slot][0][3]);
        c10 = fmaxf(c10, part[g][slot][1][0]);
        c11 = fmaxf(c11, part[g][slot][1][1]);
        c12 = fmaxf(c12, part[g][slot][1][2]);
        c13 = fmaxf(c13, part[g][slot][1][3]);
      }
      v00 = c00 - mprev0; v01 = c01 - mprev0; v02 = c02 - mprev0; v03 = c03 - mprev0;
      v10 = c10 - mprev1; v11 = c11 - mprev1; v12 = c12 - mprev1; v13 = c13 - mprev1;
      float* d0 = out0 + (size_t)(68-k)*JT + j*S1 + t0;
      float* d1 = out1 + (size_t)(68-k)*JT + j*S1 + t0;
      if (tq < 17){
        float4u w0; w0.x=v00; w0.y=v01; w0.z=v02; w0.w=v03;
        float4u w1; w1.x=v10; w1.y=v11; w1.z=v12; w1.w=v13;
        *(float4u*)d0 = w0;
        *(float4u*)d1 = w1;
        *(float4*)(&la[0][cur^1][j*72 + t0]) = make_float4(v00, v01, v02, v03);
        *(float4*)(&la[1][cur^1][j*72 + t0]) = make_float4(v10, v11, v12, v13);
        mval0 = fmaxf(fmaxf(v00, v01), fmaxf(v02, v03));
        mval1 = fmaxf(fmaxf(v10, v11), fmaxf(v12, v13));
      } else {                                           // owns only t=68
        d0[3] = v03;  d1[3] = v13;
        la[0][cur^1][j*72 + 68] = v03;
        la[1][cur^1][j*72 + 68] = v13;
        mval0 = v03;  mval1 = v13;
      }
    }
    // block max -> m[k]  (only g0 waves 0..2 hold real values)
    float mr0 = mval0, mr1 = mval1;
    #pragma unroll
    for (int o = 32; o >= 1; o >>= 1){
      mr0 = fmaxf(mr0, __shfl_down(mr0, o));
      mr1 = fmaxf(mr1, __shfl_down(mr1, o));
    }
    if (lane == 0){ red[0][w] = mr0; red[1][w] = mr1; }
    __syncthreads();                                     // (B) red + la ready
    const float mA0 = fmaxf(fmaxf(red[0][0], red[0][1]), red[0][2]);
    const float mA1 = fmaxf(fmaxf(red[1][0], red[1][1]), red[1][2]);
    if (act && gg == 0){
      float sv0, sv1;
      if (tq < 17){
        sv0 = expf(v00-mA0) + expf(v01-mA0) + expf(v02-mA0) + expf(v03-mA0);
        sv1 = expf(v10-mA1) + expf(v11-mA1) + expf(v12-mA1) + expf(v13-mA1);
      } else {
        sv0 = expf(v03-mA0);
        sv1 = expf(v13-mA1);
      }
      #pragma unroll
      for (int o = 32; o >= 1; o >>= 1){
        sv0 += __shfl_down(sv0, o);
        sv1 += __shfl_down(sv1, o);
      }
      if (lane == 0){ sums_sh[0][k][w] = sv0; sums_sh[1][k][w] = sv1; }
    }
    if (tid == 0){ m_sh[0][k] = mA0; m_sh[1][k] = mA1; }
    mprev0 = mA0; mprev1 = mA1;
    cur ^= 1;
  }
  __syncthreads();

  // ---- lse finalize + n[k] = lse_v[k] + D[k], D[k]=sum_{kk<k} m (double) ----
  if (tid == 0){
    double d0 = 0.0, d1 = 0.0;
    for (int kk = 0; kk <= NSTEP; ++kk){
      float l0, l1;
      if (kk == 0){ l0 = lse_sh[0][0]; l1 = lse_sh[1][0]; }
      else {
        l0 = m_sh[0][kk] + logf(sums_sh[0][kk][0] + sums_sh[0][kk][1] + sums_sh[0][kk][2]);
        l1 = m_sh[1][kk] + logf(sums_sh[1][kk][0] + sums_sh[1][kk][1] + sums_sh[1][kk][2]);
      }
      lse_sh[0][kk] = l0;  lse_sh[1][kk] = l1;
      n_sh[0][kk] = (float)((double)l0 + d0);
      n_sh[1][kk] = (float)((double)l1 + d1);
      d0 += (double)m_sh[0][kk];
      d1 += (double)m_sh[1][kk];
    }
  }
  __syncthreads();

  // ---- addc: alpha[K] = v[68-K] + (n[K] - lse_v[68-K]), clamp -3e38 ----
  for (int K = 0; K <= NSTEP; ++K){
    const float C0 = n_sh[0][K] - lse_sh[0][68-K];
    const float C1 = n_sh[1][K] - lse_sh[1][68-K];
    for (int e = tid; e < JT; e += 1024){
      float* r0 = out0 + (size_t)K*JT + e;
      float* r1 = out1 + (size_t)K*JT + e;
      *r0 = fmaxf(*r0 + C0, -3.0e38f);
      *r1 = fmaxf(*r1 + C1, -3.0e38f);
    }
  }
  __syncthreads();

  // ---- backtrace: both batches' serial chains interleaved for ILP ----
  {
    int c0 = 3, t20 = ls[b0];
    int c1 = 3, t21 = ls[b1];
    float* mpb0 = out + (size_t)ALPHA_N + (size_t)b0*(69*3);
    float* mpb1 = out + (size_t)ALPHA_N + (size_t)b1*(69*3);
    if (tid == 0){
      mpb0[68*3+0] = 3.f; mpb0[68*3+1] = 0.f; mpb0[68*3+2] = (float)t20;
      mpb0[67*3+1] = 0.f;
      mpb1[68*3+0] = 3.f; mpb1[68*3+1] = 0.f; mpb1[68*3+2] = (float)t21;
      mpb1[67*3+1] = 0.f;
    }
    const bool vok = tid < JT;
    const int etid = vok ? tid : 0;
    const int im = etid / S1;
    const int sm = etid - im*S1;
    float av0 = vok ? out0[1*JT + tid] : NEGINF;
    float av1 = vok ? out1[1*JT + tid] : NEGINF;
    for (int r = 1; r <= NSTEP; ++r){
      float avn0 = NEGINF, avn1 = NEGINF;
      if (r < NSTEP && vok){
        avn0 = out0[(size_t)(r+1)*JT + tid];
        avn1 = out1[(size_t)(r+1)*JT + tid];
      }
      float best0 = NEGINF, best1 = NEGINF;
      int bi0 = 0x7fffffff, bi1 = 0x7fffffff;
      if (vok){
        float q0, q1;
        if (wsmode >= 2){
          q0 = QT[(size_t)c0*QI + (size_t)t20*JT + tid];
          q1 = QT[(size_t)c1*QI + (size_t)t21*JT + tid];
        } else if (wsmode == 1){
          q0 = QW[(size_t)c0*QI + (size_t)sm*JT + im*S1 + t20];
          q1 = QW[(size_t)c1*QI + (size_t)sm*JT + im*S1 + t21];
        } else {
          q0 = Q[(size_t)c0*QI + (size_t)im*QJ + sm*S1 + t20];
          q1 = Q[(size_t)c1*QI + (size_t)im*QJ + sm*S1 + t21];
        }
        const float pv0 = P[(size_t)(b0*C9 + c0)*QJ + sm*S1 + t20];
        const float pv1 = P[(size_t)(b1*C9 + c1)*QJ + sm*S1 + t21];
        best0 = (pv0 + Tv*q0) + av0; bi0 = tid;  // exact ref association
        best1 = (pv1 + Tv*q1) + av1; bi1 = tid;
      }
      // argmax: strict > with min-index tie-break == jnp.argmax first-occurrence
      #pragma unroll
      for (int o = 32; o >= 1; o >>= 1){
        const float ov0 = __shfl_down(best0, o); const int oi0 = __shfl_down(bi0, o);
        if (ov0 > best0 || (ov0 == best0 && oi0 < bi0)){ best0 = ov0; bi0 = oi0; }
        const float ov1 = __shfl_down(best1, o); const int oi1 = __shfl_down(bi1, o);
        if (ov1 > best1 || (ov1 == best1 && oi1 < bi1)){ best1 = ov1; bi1 = oi1; }
      }
      if (lane == 0){
        sbest[0][w] = best0; sidx[0][w] = bi0;
        sbest[1][w] = best1; sidx[1][w] = bi1;
      }
      __syncthreads();
      if (tid == 0){
        float bb = sbest[0][0]; int bi = sidx[0][0];
        #pragma unroll
        for (int q = 1; q < 16; ++q)
          if (sbest[0][q] > bb || (sbest[0][q] == bb && sidx[0][q] < bi)){
            bb = sbest[0][q]; bi = sidx[0][q];
          }
        int cn = bi / S1, tn = bi - (bi/S1)*S1;
        mpb0[(68-r)*3 + 0] = (float)cn;
        mpb0[(68-r)*3 + 2] = (float)tn;
        if (r <= 67) mpb0[(67-r)*3 + 1] = (float)(tn - t20);
        sct[0] = cn; sct[1] = tn;

        bb = sbest[1][0]; bi = sidx[1][0];
        #pragma unroll
        for (int q = 1; q < 16; ++q)
          if (sbest[1][q] > bb || (sbest[1][q] == bb && sidx[1][q] < bi)){
            bb = sbest[1][q]; bi = sidx[1][q];
          }
        cn = bi / S1; tn = bi - (bi/S1)*S1;
        mpb1[(68-r)*3 + 0] = (float)cn;
        mpb1[(68-r)*3 + 2] = (float)tn;
        if (r <= 67) mpb1[(67-r)*3 + 1] = (float)(tn - t21);
        sct[2] = cn; sct[3] = tn;
      }
      __syncthreads();
      c0 = sct[0]; t20 = sct[1];
      c1 = sct[2]; t21 = sct[3];
      av0 = avn0; av1 = avn1;
    }
  }
}

// ---------------------------------------------------------------------------
extern "C" void kernel_launch(void* const* d_in, const int* in_sizes, int n_in,
                              void* d_out, int out_size, void* d_ws, size_t ws_size,
                              hipStream_t stream)
{
  const float* P  = (const float*)d_in[0];
  const float* Q  = (const float*)d_in[1];
  const float* pi = (const float*)d_in[2];
  const float* T  = (const float*)d_in[3];
  const int*   ls = (const int*)d_in[4];

  float* out = (float*)d_out;

  // ws regions (launch-invariant branches -> graph-safe):
  //   [0, QTFL)        QW  (scan-optimized Q layout)
  //   [QTFL, 2*QTFL)   QT  (backtrace-coalesced Q layout)
  int wsmode = 0; float* QW = nullptr; float* QT = nullptr;
  if (ws_size >= (size_t)QTFL*4){ wsmode = 1; QW = (float*)d_ws; }
  if (ws_size >= (size_t)2*QTFL*4){ wsmode = 2; QT = (float*)d_ws + QTFL; }

  if (wsmode >= 1) qw_kernel<<<JT, 256, 0, stream>>>(Q, QW);
  if (wsmode >= 2) qtrans_kernel<<<81, 256, 0, stream>>>(Q, QT);
  mega_kernel<<<NBATCH/2, 1024, 0, stream>>>(P, Q, pi, T, ls, out, QW, QT, wsmode);
}

// Round 7
// 2057.737 us; speedup vs baseline: 1.3414x; 1.3414x over previous
//
#include <hip/hip_runtime.h>

// Problem constants (SIZE=68, SSN=8 -> C=9, S1=69, BATCH=256)
#define C9     9
#define S1     69
#define JT     621            // C9*S1: one (class,pos) plane
#define NBATCH 256
#define NSTEP  68
#define QJ     4761           // 69*69   (Q j-stride, P s-major plane size)
#define QI     42849          // 9*69*69 (Q i-stride; also P batch stride)
#define BROW   42849          // 69 planes * 621 per-batch alpha
#define ALPHA_N (NBATCH*BROW)
#define QTFL   385664         // padded float count of one ws region
#define NEGINF (-__builtin_inff())

// Vector types with 4-byte alignment guarantee (rows have odd stride 69).
typedef float float2u __attribute__((ext_vector_type(2), aligned(4)));

// ---------------------------------------------------------------------------
// qw: QW[j][s][i][t] = Q[j][i][s][t].  9 i-values at stride 276 B from one
// base (13-bit immediate-offset friendly) and s-advance = one pointer bump.
__global__ void qw_kernel(const float* __restrict__ Q, float* __restrict__ QW)
{
  const int bl = blockIdx.x;           // j*69 + s
  const int j = bl / S1, s = bl - j*S1;
  float* dst = QW + (size_t)bl*JT;
  const float* src = Q + (size_t)j*QJ + s*S1;
  for (int f = threadIdx.x; f < JT; f += 256){
    const int i = f / S1, t = f - i*S1;
    dst[f] = src[i*QJ + t];
  }
}

// ---------------------------------------------------------------------------
// qtrans: QT[c][t][i][s] = Q[c][i][s][t]  (coalesced backtrace Q reads)
__global__ void qtrans_kernel(const float* __restrict__ Q, float* __restrict__ QT)
{
  __shared__ float tile[69*70];
  const int pl = blockIdx.x;           // c*9 + i
  const int c = pl / 9, i = pl - c*9;
  const float* src = Q + (size_t)pl*QJ;
  for (int f = threadIdx.x; f < QJ; f += 256){
    const int s = f / S1, t = f - s*S1;
    tile[s*70 + t] = src[f];
  }
  __syncthreads();
  float* dst = QT + (size_t)c*QI + i*S1;     // + t*621 + s
  for (int f = threadIdx.x; f < QJ; f += 256){
    const int t = f / S1, s = f - t*S1;
    dst[t*JT + s] = tile[s*70 + t];
  }
}

// ---------------------------------------------------------------------------
// scan23: partial max-plus over 23 consecutive s rows (caller pre-offsets
// bases by s_lo).  t-PAIR granularity: Q ping-pong = 9 x float2 x 2 buf =
// 36 VGPR, sized for the 64-VGPR cap the compiler pins on 1024-thread
// blocks (rounds 4-6: t-quad's 72-VGPR Q buffer spilled, WRITE_SIZE 3x).
// P is single-buffered inside CM (1/10 of traffic; ~40 VALU ops of hiding).
// SI = Q i-stride (floats), SS = Q s-stride (floats).
template<int SI, int SS>
__device__ __forceinline__ float2u scan23(const float* __restrict__ qb,
                                          const float* __restrict__ pb,
                                          const float* __restrict__ laS,
                                          const float Tv)
{
#define LD(QB, S) { \
  const float* q_ = qb + (S)*SS; \
  _Pragma("unroll") \
  for (int i_ = 0; i_ < C9; ++i_) QB[i_] = *(const float2u*)(q_ + i_*SI); }
#define CM(QB, S) { \
  const float2u pv_ = *(const float2u*)(pb + (S)*S1); \
  float r0 = NEGINF, r1 = NEGINF; \
  _Pragma("unroll") \
  for (int i_ = 0; i_ < C9; ++i_){ \
    const float lv_ = laS[i_*72 + (S)]; \
    r0 = fmaxf(r0, fmaf(Tv, QB[i_].x, lv_)); \
    r1 = fmaxf(r1, fmaf(Tv, QB[i_].y, lv_)); \
  } \
  acc.x = fmaxf(acc.x, pv_.x + r0); \
  acc.y = fmaxf(acc.y, pv_.y + r1); }

  float2u acc; acc.x = acc.y = NEGINF;
  float2u qA[C9], qB[C9];
  LD(qA, 0)
  int s = 0;
  for (; s + 2 < 23; s += 2){
    LD(qB, s+1)
    CM(qA, s)
    LD(qA, s+2)
    CM(qB, s+1)
  }
  CM(qA, 22)      // width 23 is odd: tail compute
  return acc;
#undef LD
#undef CM
}

// ---------------------------------------------------------------------------
// mega v7: one batch per block, grid 256 (all CUs).  1024 threads = 16 waves
// (4 waves/SIMD, 2x round-2's TLP): 3 s-groups x 315 (j,t-pair) slots = 945
// active; s-ranges {0-22, 23-45, 46-68} partition exactly (no duplicate
// work).  tp=34 clamps its pair base to t=67: loads stay in-bounds, the
// duplicate t=67 value is max-idempotent and masked out of the exp-sum.
// Two barriers per step; lse finalize deferred via sums_sh.
__global__ __launch_bounds__(1024) void mega_kernel(
    const float* __restrict__ P, const float* __restrict__ Q,
    const float* __restrict__ pi, const float* __restrict__ Tp,
    const int* __restrict__ ls, float* __restrict__ out,
    const float* __restrict__ QW, const float* __restrict__ QT, int wsmode)
{
  __shared__ __align__(16) float la[2][C9*72];   // la[buf][i*72 + s]
  __shared__ float part[2][315][3];              // groups 1..2 partials; stride 3
  __shared__ float red[16];
  __shared__ float m_sh[NSTEP+1], lse_sh[NSTEP+1], n_sh[NSTEP+1];
  __shared__ float sums_sh[NSTEP+1][5];          // per-(k, g0-wave) exp sums
  __shared__ float sbest[16];
  __shared__ int   sidx[16];
  __shared__ int   sct[2];

  const int tid  = threadIdx.x;
  const int w    = tid >> 6;
  const int lane = tid & 63;
  const int b    = blockIdx.x;
  const bool act = tid < 945;
  const int gg   = act ? tid / 315 : 2;          // s-group 0..2
  const int slot = act ? tid - gg*315 : 314;
  const int j    = slot / 35;                    // output class 0..8
  const int tp   = slot - j*35;                  // t-pair 0..34
  const bool own2 = (tp < 34);
  const int t0   = own2 ? 2*tp : 67;             // tp=34: clamp, owns only t=68
  const int s_lo = gg*23;                        // {0,23,46} exact partition
  const float Tv = Tp[0];

  float* outb = out + (size_t)b*BROW;

  // ---- prep: v[0] raw (pi at s==0, else -inf); m[0], lse_v[0] ----
  for (int e = tid; e < JT; e += 1024){
    const int i = e / S1, s = e - i*S1;
    const float v0 = (s == 0) ? pi[i] : NEGINF;
    outb[68*JT + e] = v0;
    la[0][i*72 + s] = v0;
  }
  if (tid == 0){
    float mx = pi[0];
    #pragma unroll
    for (int c = 1; c < C9; ++c) mx = fmaxf(mx, pi[c]);
    float sm = 0.f;
    #pragma unroll
    for (int c = 0; c < C9; ++c) sm += expf(pi[c] - mx);
    m_sh[0]   = mx;
    lse_sh[0] = mx + logf(sm);
  }
  __syncthreads();
  float mprev = m_sh[0];

  const bool useQW = (wsmode >= 1);
  // QW[j][s][i][t]: j-stride QI; s-stride JT; i-stride S1.
  const float* qw_b = QW + (size_t)j*QI + (size_t)s_lo*JT + t0;
  // Raw Q[j][i][s][t]: i-stride QI; s-stride S1.
  const float* qr_b = Q + (size_t)j*QJ + s_lo*S1 + t0;
  const float* p_b  = P + (size_t)(b*C9 + j)*QJ + s_lo*S1 + t0;

  // ---- 68 max-plus steps ----
  int cur = 0;
  for (int k = 1; k <= NSTEP; ++k){
    const float* laS = la[cur] + s_lo;
    float2u acc;
    if (act){
      if (useQW) acc = scan23<S1, JT>(qw_b, p_b, laS, Tv);
      else       acc = scan23<QI, S1>(qr_b, p_b, laS, Tv);
      if (gg > 0){
        part[gg-1][slot][0] = acc.x;
        part[gg-1][slot][1] = acc.y;
      }
    }
    __syncthreads();                                     // (A) partials ready

    float mval = NEGINF;
    float v0 = 0.f, v1 = 0.f;
    if (act && gg == 0){
      const float c0 = fmaxf(fmaxf(acc.x, part[0][slot][0]), part[1][slot][0]);
      const float c1 = fmaxf(fmaxf(acc.y, part[0][slot][1]), part[1][slot][1]);
      v0 = c0 - mprev;
      v1 = c1 - mprev;
      float* dst = outb + (size_t)(68-k)*JT + j*S1 + t0;
      if (own2){
        float2u vv; vv.x = v0; vv.y = v1;
        *(float2u*)dst = vv;
        la[cur^1][j*72 + t0]     = v0;
        la[cur^1][j*72 + t0 + 1] = v1;
        mval = fmaxf(v0, v1);
      } else {                                           // owns only t=68
        dst[1] = v1;
        la[cur^1][j*72 + 68] = v1;
        mval = v1;                                       // t=67 dup excluded
      }
    }
    // block max -> m[k]  (only g0's waves 0..4 hold real values)
    float mr = mval;
    #pragma unroll
    for (int o = 32; o >= 1; o >>= 1) mr = fmaxf(mr, __shfl_down(mr, o));
    if (lane == 0) red[w] = mr;
    __syncthreads();                                     // (B) red + la ready
    float mA = red[0];
    #pragma unroll
    for (int q = 1; q < 5; ++q) mA = fmaxf(mA, red[q]);
    if (act && gg == 0){
      float sv = own2 ? (expf(v0 - mA) + expf(v1 - mA)) : expf(v1 - mA);
      #pragma unroll
      for (int o = 32; o >= 1; o >>= 1) sv += __shfl_down(sv, o);
      if (lane == 0) sums_sh[k][w] = sv;
    }
    if (tid == 0) m_sh[k] = mA;
    mprev = mA;
    cur ^= 1;
  }
  __syncthreads();

  // ---- lse finalize + n[k] = lse_v[k] + D[k], D[k]=sum_{kk<k} m (double) ----
  if (tid == 0){
    double dd = 0.0;
    for (int kk = 0; kk <= NSTEP; ++kk){
      float lse;
      if (kk == 0) lse = lse_sh[0];
      else {
        float S = sums_sh[kk][0];
        #pragma unroll
        for (int q = 1; q < 5; ++q) S += sums_sh[kk][q];
        lse = m_sh[kk] + logf(S);
      }
      lse_sh[kk] = lse;
      n_sh[kk] = (float)((double)lse + dd);
      dd += (double)m_sh[kk];
    }
  }
  __syncthreads();

  // ---- addc: alpha[K] = v[68-K] + (n[K] - lse_v[68-K]), clamp -3e38 ----
  for (int K = 0; K <= NSTEP; ++K){
    const float Cst = n_sh[K] - lse_sh[68-K];
    for (int e = tid; e < JT; e += 1024){
      float* r = outb + (size_t)K*JT + e;
      *r = fmaxf(*r + Cst, -3.0e38f);
    }
  }
  __syncthreads();

  // ---- backtrace: 621 candidates, one per thread ----
  {
    int c = 3, t2 = ls[b];
    float* mpb = out + (size_t)ALPHA_N + (size_t)b*(69*3);
    if (tid == 0){
      mpb[68*3+0] = 3.f; mpb[68*3+1] = 0.f; mpb[68*3+2] = (float)t2;
      mpb[67*3+1] = 0.f;   // l_0 = 0 after the shift
    }
    const bool vok = tid < JT;
    const int etid = vok ? tid : 0;
    const int im = etid / S1;
    const int sm = etid - im*S1;
    float av = vok ? outb[1*JT + tid] : NEGINF;
    for (int r = 1; r <= NSTEP; ++r){
      float avn = NEGINF;
      if (r < NSTEP && vok) avn = outb[(size_t)(r+1)*JT + tid];
      float best = NEGINF; int bidx = 0x7fffffff;
      if (vok){
        float qv;
        if (wsmode >= 2)      qv = QT[(size_t)c*QI + (size_t)t2*JT + tid];
        else if (wsmode == 1) qv = QW[(size_t)c*QI + (size_t)sm*JT + im*S1 + t2];
        else                  qv = Q[(size_t)c*QI + (size_t)im*QJ + sm*S1 + t2];
        const float pv = P[(size_t)(b*C9 + c)*QJ + sm*S1 + t2];
        best = (pv + Tv*qv) + av;   // exact ref association
        bidx = tid;
      }
      // argmax: strict > with min-index tie-break == jnp.argmax first-occurrence
      #pragma unroll
      for (int o = 32; o >= 1; o >>= 1){
        const float ov = __shfl_down(best, o); const int oi = __shfl_down(bidx, o);
        if (ov > best || (ov == best && oi < bidx)){ best = ov; bidx = oi; }
      }
      if (lane == 0){ sbest[w] = best; sidx[w] = bidx; }
      __syncthreads();
      if (tid == 0){
        float bb = sbest[0]; int bi = sidx[0];
        #pragma unroll
        for (int q = 1; q < 16; ++q)
          if (sbest[q] > bb || (sbest[q] == bb && sidx[q] < bi)){
            bb = sbest[q]; bi = sidx[q];
          }
        const int cn = bi / S1, tn = bi - cn*S1;
        mpb[(68-r)*3 + 0] = (float)cn;
        mpb[(68-r)*3 + 2] = (float)tn;
        if (r <= 67) mpb[(67-r)*3 + 1] = (float)(tn - t2);
        sct[0] = cn; sct[1] = tn;
      }
      __syncthreads();
      c = sct[0]; t2 = sct[1];
      av = avn;
    }
  }
}

// ---------------------------------------------------------------------------
extern "C" void kernel_launch(void* const* d_in, const int* in_sizes, int n_in,
                              void* d_out, int out_size, void* d_ws, size_t ws_size,
                              hipStream_t stream)
{
  const float* P  = (const float*)d_in[0];
  const float* Q  = (const float*)d_in[1];
  const float* pi = (const float*)d_in[2];
  const float* T  = (const float*)d_in[3];
  const int*   ls = (const int*)d_in[4];

  float* out = (float*)d_out;

  // ws regions (launch-invariant branches -> graph-safe):
  //   [0, QTFL)        QW  (scan-optimized Q layout)
  //   [QTFL, 2*QTFL)   QT  (backtrace-coalesced Q layout)
  int wsmode = 0; float* QW = nullptr; float* QT = nullptr;
  if (ws_size >= (size_t)QTFL*4){ wsmode = 1; QW = (float*)d_ws; }
  if (ws_size >= (size_t)2*QTFL*4){ wsmode = 2; QT = (float*)d_ws + QTFL; }

  if (wsmode >= 1) qw_kernel<<<JT, 256, 0, stream>>>(Q, QW);
  if (wsmode >= 2) qtrans_kernel<<<81, 256, 0, stream>>>(Q, QT);
  mega_kernel<<<NBATCH, 1024, 0, stream>>>(P, Q, pi, T, ls, out, QW, QT, wsmode);
}